// Round 7
// baseline (830.256 us; speedup 1.0000x reference)
//
#include <hip/hip_runtime.h>
#include <stdint.h>

#define NPROP 2048
#define NCLS  2
#define KDET  100
#define BT    512
#define NMS_TH 0.4f

// write-only sinks to keep microbenchmarks live (never read; deterministic overwrite)
__device__ uint64_t g_sink64[16];
__device__ float    g_fsink;

// decode the monotone-encoded score from the high word of a sort key
__device__ __forceinline__ float dec_score(uint64_t k) {
    uint32_t u = ~(uint32_t)(k >> 32);
    uint32_t bits = (u & 0x80000000u) ? (u & 0x7FFFFFFFu) : ~u;
    return __uint_as_float(bits);
}

__global__ __launch_bounds__(BT) void PRISM_71511205479155_kernel(
    const float* __restrict__ clss,   // [B,N,2]
    const float* __restrict__ regs,   // [B,N,4]
    const float* __restrict__ qlts,   // [B,N]
    const float* __restrict__ props,  // [B,N,4]
    float* __restrict__ out,          // boxes[B*K*4] | scores[B*K] | classes[B*K]
    int B)
{
    __shared__ float4   sbox[NPROP];          // decoded+clipped boxes (orig coords)
    __shared__ uint64_t skey[NPROP];          // sort scratch (phi layout) / sorted keys (true layout)
    __shared__ uint64_t s_colpart[8 * 64];    // per-wave partial column masks
    __shared__ uint64_t s_inpart[8];          // per-wave incoming-suppression ballots
    __shared__ float4   s_kbox[KDET];         // keeper boxes in OFFSET coords
    __shared__ float    s_karea[KDET];        // keeper areas (offset coords)
    __shared__ int      s_keep[KDET];         // sorted positions of keepers
    __shared__ int      s_maxc, s_kept, s_nvalid;

    const int b    = blockIdx.x;
    const int tid  = threadIdx.x;
    const int lane = tid & 63;
    const int wv   = tid >> 6;                  // 8 waves
    const int idxBase = (wv << 8) | (lane << 2); // element idx(r) = idxBase + r (consecutive!)
    const float CLIPV = 4.135166556742356f;     // log(1000/16)

    if (tid == 0) { s_maxc = 0; s_kept = 0; s_nvalid = NPROP; }
    __syncthreads();   // init visible before any atomic below

    // ---- Phase A: decode, clip, score, build sort keys (4 consecutive elems/thread) ----
    uint64_t key[4];
    float thmax = 0.0f;
#pragma unroll
    for (int r = 0; r < 4; ++r) {
        int i = idxBase + r;
        float4 p  = ((const float4*)props)[b * NPROP + i];
        float4 rg = ((const float4*)regs)[b * NPROP + i];
        float2 cc = ((const float2*)clss)[b * NPROP + i];
        float  qv = qlts[(size_t)b * NPROP + i];

        float w  = __fsub_rn(p.z, p.x);
        float h  = __fsub_rn(p.w, p.y);
        float cx = __fadd_rn(p.x, __fmul_rn(0.5f, w));
        float cy = __fadd_rn(p.y, __fmul_rn(0.5f, h));
        float dx = __fdiv_rn(rg.x, 10.0f);
        float dy = __fdiv_rn(rg.y, 10.0f);
        float dw = fminf(__fdiv_rn(rg.z, 5.0f), CLIPV);
        float dh = fminf(__fdiv_rn(rg.w, 5.0f), CLIPV);
        float pcx = __fadd_rn(__fmul_rn(dx, w), cx);
        float pcy = __fadd_rn(__fmul_rn(dy, h), cy);
        float pw  = __fmul_rn(expf(dw), w);
        float ph  = __fmul_rn(expf(dh), h);
        float x1 = __fsub_rn(pcx, __fmul_rn(0.5f, pw));
        float y1 = __fsub_rn(pcy, __fmul_rn(0.5f, ph));
        float x2 = __fadd_rn(pcx, __fmul_rn(0.5f, pw));
        float y2 = __fadd_rn(pcy, __fmul_rn(0.5f, ph));
        x1 = fminf(fmaxf(x1, 0.0f), 512.0f);
        y1 = fminf(fmaxf(y1, 0.0f), 512.0f);
        x2 = fminf(fmaxf(x2, 0.0f), 512.0f);
        y2 = fminf(fmaxf(y2, 0.0f), 512.0f);
        bool small_ok = (__fsub_rn(x2, x1) >= 0.01f) && (__fsub_rn(y2, y1) >= 0.01f);

        float m  = fmaxf(cc.x, cc.y);
        float e0 = expf(__fsub_rn(cc.x, m));
        float e1 = expf(__fsub_rn(cc.y, m));
        float raw = __fdiv_rn(e1, __fadd_rn(e0, e1));
        float sq  = __fdiv_rn(1.0f, __fadd_rn(1.0f, expf(-qv)));
        float score = __fmul_rn(sq, raw);
        bool valid = (raw > 0.05f) && small_ok;
        float masked = valid ? score : -1.0f;

        sbox[i] = make_float4(x1, y1, x2, y2);
        uint32_t fb = __float_as_uint(masked);
        uint32_t u  = (fb & 0x80000000u) ? ~fb : (fb | 0x80000000u); // monotone encode
        key[r] = ((uint64_t)(~u) << 32) | (uint32_t)i;               // asc = score desc, idx asc

        thmax = fmaxf(thmax, fmaxf(fmaxf(x1, y1), fmaxf(x2, y2)));
    }
    atomicMax(&s_maxc, __float_as_int(thmax));   // coords >= 0: int cmp == float cmp

    // ---- Phase B: bitonic sort of 2048 keys ----
    // idx = [wv(3b)][lane(6b)][r(2b)]: j<=2 -> register; 4<=j<=128 -> shfl_xor(j>>2);
    // j>=256 -> LDS via phi-swizzled storage phi(idx) = (idx>>2) | ((idx&3)<<9).
    for (int k = 2; k <= NPROP; k <<= 1) {
        for (int j = k >> 1; j > 0; j >>= 1) {
            if (j >= 256) {
                __syncthreads();
#pragma unroll
                for (int r = 0; r < 4; ++r) {
                    int idx = idxBase + r;
                    skey[(idx >> 2) | ((idx & 3) << 9)] = key[r];
                }
                __syncthreads();
#pragma unroll
                for (int r = 0; r < 4; ++r) {
                    int idx  = idxBase + r;
                    int pidx = idx ^ j;
                    uint64_t o = skey[(pidx >> 2) | ((pidx & 3) << 9)];
                    bool takeMin = (((idx & k) == 0) == ((idx & j) == 0));
                    bool lt = key[r] < o;
                    uint64_t mn = lt ? key[r] : o, mx = lt ? o : key[r];
                    key[r] = takeMin ? mn : mx;
                }
            } else if (j >= 4) {
                int lx = j >> 2;
#pragma unroll
                for (int r = 0; r < 4; ++r) {
                    int idx = idxBase + r;
                    uint64_t o = __shfl_xor(key[r], lx, 64);
                    bool takeMin = (((idx & k) == 0) == ((lane & lx) == 0));
                    bool lt = key[r] < o;
                    uint64_t mn = lt ? key[r] : o, mx = lt ? o : key[r];
                    key[r] = takeMin ? mn : mx;
                }
            } else {
                // j == 1 or 2: register pairs (r, r|j)
#pragma unroll
                for (int r = 0; r < 4; ++r) {
                    if ((r & j) == 0) {
                        int rh = r | j;
                        int idx = idxBase + r;
                        bool up = ((idx & k) == 0);
                        uint64_t a = key[r], c2 = key[rh];
                        bool lt = a < c2;
                        uint64_t mn = lt ? a : c2, mx = lt ? c2 : a;
                        key[r] = up ? mn : mx; key[rh] = up ? mx : mn;
                    }
                }
            }
        }
    }

    // publish sorted keys at TRUE layout (barrier: last LDS-stage reads must finish)
    __syncthreads();
#pragma unroll
    for (int r = 0; r < 4; ++r) skey[idxBase + r] = key[r];

    // valid prefix length from registers: first element with top bit set
    {
        int fi = 4;
#pragma unroll
        for (int r = 3; r >= 0; --r) if ((key[r] >> 63) != 0) fi = r;
        uint64_t anyb = __ballot(fi < 4);
        if (anyb) {
            int L = (int)__builtin_ctzll(anyb);
            int fiL = __shfl(fi, L);
            if (lane == 0) atomicMin(&s_nvalid, (wv << 8) + (L << 2) + fiL);
        }
    }
    __syncthreads();

    const float off = __fadd_rn(__int_as_float(s_maxc), 1.0f); // class-1 batched-NMS offset

    // ---- Phase C: windowed greedy NMS (exact reference semantics) ----
    int c = 0;
    while (true) {
        __syncthreads();
        int kept = s_kept;
        int nv   = s_nvalid;
        if (c >= nv || kept >= KDET) break;
        int W = min(64, nv - c);
        bool have = (lane < W);

        // this lane's candidate in OFFSET coords + area (reference op order)
        float qx1 = 0.f, qy1 = 0.f, qx2 = 0.f, qy2 = 0.f, qa = 0.f;
        if (have) {
            float4 bx = sbox[(uint32_t)skey[c + lane]];
            qx1 = __fadd_rn(bx.x, off); qy1 = __fadd_rn(bx.y, off);
            qx2 = __fadd_rn(bx.z, off); qy2 = __fadd_rn(bx.w, off);
            qa  = __fmul_rn(__fsub_rn(qx2, qx1), __fsub_rn(qy2, qy1));
        }

        // in-window rows via shuffle broadcast; accumulate OWN column bits
        uint64_t colpart = 0;
#pragma unroll
        for (int t = 0; t < 8; ++t) {
            int i = wv + (t << 3);
            bool rowok = (i < W);
            int isrc = rowok ? i : 0;
            float rx1 = __shfl(qx1, isrc, 64);
            float ry1 = __shfl(qy1, isrc, 64);
            float rx2 = __shfl(qx2, isrc, 64);
            float ry2 = __shfl(qy2, isrc, 64);
            float ra  = __shfl(qa , isrc, 64);
            float ltx = fmaxf(rx1, qx1), lty = fmaxf(ry1, qy1);
            float rbx = fminf(rx2, qx2), rby = fminf(ry2, qy2);
            float iw = fmaxf(__fsub_rn(rbx, ltx), 0.0f);
            float ih = fmaxf(__fsub_rn(rby, lty), 0.0f);
            float inter = __fmul_rn(iw, ih);
            float denom = __fadd_rn(__fsub_rn(__fadd_rn(ra, qa), inter), 1e-9f);
            float iou   = __fdiv_rn(inter, denom);
            bool pred = rowok && have && (lane > i) && (iou > NMS_TH);
            uint64_t bm = (uint64_t)__ballot(pred);
            colpart |= ((bm >> lane) & 1ull) << isrc;
        }
        s_colpart[(wv << 6) | lane] = colpart;

        // incoming suppression by prior-window keepers (offset boxes + areas cached)
        bool supin = false;
        if (have) {
            for (int ki = wv; ki < kept; ki += 8) {
                float4 ko = s_kbox[ki];
                float  ka = s_karea[ki];
                float ltx = fmaxf(ko.x, qx1), lty = fmaxf(ko.y, qy1);
                float rbx = fminf(ko.z, qx2), rby = fminf(ko.w, qy2);
                float iw = fmaxf(__fsub_rn(rbx, ltx), 0.0f);
                float ih = fmaxf(__fsub_rn(rby, lty), 0.0f);
                float inter = __fmul_rn(iw, ih);
                float denom = __fadd_rn(__fsub_rn(__fadd_rn(ka, qa), inter), 1e-9f);
                supin = supin || (__fdiv_rn(inter, denom) > NMS_TH);
            }
        }
        uint64_t inb = (uint64_t)__ballot(supin);
        if (lane == 0) s_inpart[wv] = inb;
        __syncthreads();

        // ballot-driven greedy resolve of the window — wave 0
        if (wv == 0) {
            uint64_t col = 0, insup = 0;
#pragma unroll
            for (int w2 = 0; w2 < 8; ++w2) {
                col   |= s_colpart[(w2 << 6) | lane];
                insup |= s_inpart[w2];
            }
            bool killed = ((insup >> lane) & 1ull) != 0ull;
            uint64_t remain = (W == 64) ? ~0ull : ((1ull << W) - 1ull);
            int k2 = kept;
            int myNew = 0;
            while (k2 < KDET) {
                uint64_t aliveB = (uint64_t)__ballot(!killed) & remain;
                if (!aliveB) break;
                int i = (int)__builtin_ctzll(aliveB);     // next keeper
                if (lane == (k2 - kept)) myNew = i;       // capture per-keeper idx
                if (lane == 0) s_keep[k2] = c + i;
                k2++;
                killed = killed || (((col >> i) & 1ull) != 0ull);
                remain = (i < 63) ? (remain & (~0ull << (i + 1))) : 0ull;
            }
            int nNew = k2 - kept;
            if (lane == 0) s_kept = k2;
            if (lane < nNew) {                            // cache keeper offset box + area
                float4 bx = sbox[(uint32_t)skey[c + myNew]];
                float kx1 = __fadd_rn(bx.x, off), ky1 = __fadd_rn(bx.y, off);
                float kx2 = __fadd_rn(bx.z, off), ky2 = __fadd_rn(bx.w, off);
                s_kbox[kept + lane]  = make_float4(kx1, ky1, kx2, ky2);
                s_karea[kept + lane] = __fmul_rn(__fsub_rn(kx2, kx1), __fsub_rn(ky2, ky1));
            }
        }
        c += W;
    }
    __syncthreads();

    // ---- Phase D: parallel output write + zero-fill ----
    float* out_boxes  = out;
    float* out_scores = out + (size_t)B * KDET * 4;
    float* out_cls    = out + (size_t)B * KDET * 5;
    int kept = s_kept;
    for (int s = tid; s < KDET; s += BT) {
        float* ob = out_boxes + ((size_t)b * KDET + s) * 4;
        if (s < kept) {
            uint64_t kk = skey[s_keep[s]];
            float4 bx = sbox[(uint32_t)kk];
            ob[0] = bx.x; ob[1] = bx.y; ob[2] = bx.z; ob[3] = bx.w;
            out_scores[(size_t)b * KDET + s] = dec_score(kk);
            out_cls[(size_t)b * KDET + s]    = 1.0f;
        } else {
            ob[0] = 0.0f; ob[1] = 0.0f; ob[2] = 0.0f; ob[3] = 0.0f;
            out_scores[(size_t)b * KDET + s] = 0.0f;
            out_cls[(size_t)b * KDET + s]    = 0.0f;
        }
    }
}

// ===================== diagnostic microbenchmarks =====================

// clockMICRO: 150,000-deep dependent v_fma_f32 chain = 600,000 cycles exactly.
// dur_us => effective clock: 250us = 2.4 GHz, 600us = 1.0 GHz.
__global__ __launch_bounds__(64) void clockMICRO_PRISM_71511205479155(float seed) {
    float x = seed + (float)threadIdx.x;
    float a = 1.0000001f;
    float c2 = 1.0e-7f;
    for (int i = 0; i < 37500; ++i) {
        asm volatile("v_fma_f32 %0, %1, %0, %2" : "+v"(x) : "v"(a), "v"(c2));
        asm volatile("v_fma_f32 %0, %1, %0, %2" : "+v"(x) : "v"(a), "v"(c2));
        asm volatile("v_fma_f32 %0, %1, %0, %2" : "+v"(x) : "v"(a), "v"(c2));
        asm volatile("v_fma_f32 %0, %1, %0, %2" : "+v"(x) : "v"(a), "v"(c2));
    }
    if (threadIdx.x == 0) g_fsink = x;   // write-only sink, deterministic
}

// sortMICRO: Phase B (identical code/LDS/barriers) x 8 reps on synthetic keys.
// Bitonic is comparison-oblivious => cost is data-independent.
__global__ __launch_bounds__(BT) void sortMICRO_PRISM_71511205479155(int reps) {
    __shared__ uint64_t skey[NPROP];
    const int tid  = threadIdx.x;
    const int lane = tid & 63;
    const int wv   = tid >> 6;
    const int idxBase = (wv << 8) | (lane << 2);

    uint64_t key[4];
#pragma unroll
    for (int r = 0; r < 4; ++r)
        key[r] = (uint64_t)(idxBase + r) * 0x9E3779B97F4A7C15ull
               ^ ((uint64_t)(blockIdx.x + 1) * 1315423911ull);

    for (int rep = 0; rep < reps; ++rep) {
        for (int k = 2; k <= NPROP; k <<= 1) {
            for (int j = k >> 1; j > 0; j >>= 1) {
                if (j >= 256) {
                    __syncthreads();
#pragma unroll
                    for (int r = 0; r < 4; ++r) {
                        int idx = idxBase + r;
                        skey[(idx >> 2) | ((idx & 3) << 9)] = key[r];
                    }
                    __syncthreads();
#pragma unroll
                    for (int r = 0; r < 4; ++r) {
                        int idx  = idxBase + r;
                        int pidx = idx ^ j;
                        uint64_t o = skey[(pidx >> 2) | ((pidx & 3) << 9)];
                        bool takeMin = (((idx & k) == 0) == ((idx & j) == 0));
                        bool lt = key[r] < o;
                        uint64_t mn = lt ? key[r] : o, mx = lt ? o : key[r];
                        key[r] = takeMin ? mn : mx;
                    }
                } else if (j >= 4) {
                    int lx = j >> 2;
#pragma unroll
                    for (int r = 0; r < 4; ++r) {
                        int idx = idxBase + r;
                        uint64_t o = __shfl_xor(key[r], lx, 64);
                        bool takeMin = (((idx & k) == 0) == ((lane & lx) == 0));
                        bool lt = key[r] < o;
                        uint64_t mn = lt ? key[r] : o, mx = lt ? o : key[r];
                        key[r] = takeMin ? mn : mx;
                    }
                } else {
#pragma unroll
                    for (int r = 0; r < 4; ++r) {
                        if ((r & j) == 0) {
                            int rh = r | j;
                            int idx = idxBase + r;
                            bool up = ((idx & k) == 0);
                            uint64_t a = key[r], c2 = key[rh];
                            bool lt = a < c2;
                            uint64_t mn = lt ? a : c2, mx = lt ? c2 : a;
                            key[r] = up ? mn : mx; key[rh] = up ? mx : mn;
                        }
                    }
                }
            }
        }
        __syncthreads();
    }

    uint64_t acc = key[0] ^ key[1] ^ key[2] ^ key[3];
    if (tid == 0) g_sink64[blockIdx.x] = acc;   // write-only sink, deterministic
}

extern "C" void kernel_launch(void* const* d_in, const int* in_sizes, int n_in,
                              void* d_out, int out_size, void* d_ws, size_t ws_size,
                              hipStream_t stream) {
    const float* clss  = (const float*)d_in[0];  // [B,N,2]
    const float* regs  = (const float*)d_in[1];  // [B,N,4]
    const float* qlts  = (const float*)d_in[2];  // [B,N,1]
    const float* props = (const float*)d_in[3];  // [B,N,4]
    float* out = (float*)d_out;

    int B = in_sizes[0] / (NPROP * NCLS);

    // 1) the real kernel (unchanged from validated R5) -> d_out
    PRISM_71511205479155_kernel<<<B, BT, 0, stream>>>(clss, regs, qlts, props, out, B);
    // 2) clock probe: 600k-cycle dependent FMA chain, 1 wave
    clockMICRO_PRISM_71511205479155<<<1, 64, 0, stream>>>(1.0f);
    // 3) sort probe: 8x Phase B under identical occupancy conditions
    sortMICRO_PRISM_71511205479155<<<B, BT, 0, stream>>>(8);
}

// Round 8
// 54.359 us; speedup vs baseline: 15.2736x; 15.2736x over previous
//
#include <hip/hip_runtime.h>
#include <stdint.h>

#define NPROP 2048
#define NCLS  2
#define KDET  100
#define BT    512
#define NMS_TH 0.4f

// decode the monotone-encoded score from the high word of a sort key
__device__ __forceinline__ float dec_score(uint64_t k) {
    uint32_t u = ~(uint32_t)(k >> 32);
    uint32_t bits = (u & 0x80000000u) ? (u & 0x7FFFFFFFu) : ~u;
    return __uint_as_float(bits);
}

// decode+clip+score one proposal: bit-identical to the validated R5 path
__device__ __forceinline__ void decode_one(
    const float* __restrict__ clss, const float* __restrict__ regs,
    const float* __restrict__ qlts, const float* __restrict__ props,
    int b, int i, float4& boxOut, uint64_t& keyOut, float& mxOut)
{
    const float CLIPV = 4.135166556742356f;   // log(1000/16)
    float4 p  = ((const float4*)props)[b * NPROP + i];
    float4 rg = ((const float4*)regs)[b * NPROP + i];
    float2 cc = ((const float2*)clss)[b * NPROP + i];
    float  qv = qlts[(size_t)b * NPROP + i];

    float w  = __fsub_rn(p.z, p.x);
    float h  = __fsub_rn(p.w, p.y);
    float cx = __fadd_rn(p.x, __fmul_rn(0.5f, w));
    float cy = __fadd_rn(p.y, __fmul_rn(0.5f, h));
    float dx = __fdiv_rn(rg.x, 10.0f);
    float dy = __fdiv_rn(rg.y, 10.0f);
    float dw = fminf(__fdiv_rn(rg.z, 5.0f), CLIPV);
    float dh = fminf(__fdiv_rn(rg.w, 5.0f), CLIPV);
    float pcx = __fadd_rn(__fmul_rn(dx, w), cx);
    float pcy = __fadd_rn(__fmul_rn(dy, h), cy);
    float pw  = __fmul_rn(expf(dw), w);
    float ph  = __fmul_rn(expf(dh), h);
    float x1 = __fsub_rn(pcx, __fmul_rn(0.5f, pw));
    float y1 = __fsub_rn(pcy, __fmul_rn(0.5f, ph));
    float x2 = __fadd_rn(pcx, __fmul_rn(0.5f, pw));
    float y2 = __fadd_rn(pcy, __fmul_rn(0.5f, ph));
    x1 = fminf(fmaxf(x1, 0.0f), 512.0f);
    y1 = fminf(fmaxf(y1, 0.0f), 512.0f);
    x2 = fminf(fmaxf(x2, 0.0f), 512.0f);
    y2 = fminf(fmaxf(y2, 0.0f), 512.0f);
    bool small_ok = (__fsub_rn(x2, x1) >= 0.01f) && (__fsub_rn(y2, y1) >= 0.01f);

    float m  = fmaxf(cc.x, cc.y);
    float e0 = expf(__fsub_rn(cc.x, m));
    float e1 = expf(__fsub_rn(cc.y, m));
    float raw = __fdiv_rn(e1, __fadd_rn(e0, e1));
    float sq  = __fdiv_rn(1.0f, __fadd_rn(1.0f, expf(-qv)));
    float score = __fmul_rn(sq, raw);
    bool valid = (raw > 0.05f) && small_ok;
    float masked = valid ? score : -1.0f;

    boxOut = make_float4(x1, y1, x2, y2);
    uint32_t fb = __float_as_uint(masked);
    uint32_t u  = (fb & 0x80000000u) ? ~fb : (fb | 0x80000000u); // monotone encode
    keyOut = ((uint64_t)(~u) << 32) | (uint32_t)i;               // asc = score desc, idx asc
    mxOut = fmaxf(fmaxf(x1, y1), fmaxf(x2, y2));
}

// register-resident bitonic sort of 2048 u64 keys (4 consecutive/thread)
// idx = [wv(3b)][lane(6b)][r(2b)]: j<=2 reg; 4<=j<=128 shfl_xor(j>>2); j>=256 LDS (phi swizzle)
__device__ __forceinline__ void bitonic2048(uint64_t key[4], uint64_t* skey,
                                            int idxBase, int lane)
{
    for (int k = 2; k <= NPROP; k <<= 1) {
        for (int j = k >> 1; j > 0; j >>= 1) {
            if (j >= 256) {
                __syncthreads();
#pragma unroll
                for (int r = 0; r < 4; ++r) {
                    int idx = idxBase + r;
                    skey[(idx >> 2) | ((idx & 3) << 9)] = key[r];
                }
                __syncthreads();
#pragma unroll
                for (int r = 0; r < 4; ++r) {
                    int idx  = idxBase + r;
                    int pidx = idx ^ j;
                    uint64_t o = skey[(pidx >> 2) | ((pidx & 3) << 9)];
                    bool takeMin = (((idx & k) == 0) == ((idx & j) == 0));
                    bool lt = key[r] < o;
                    uint64_t mn = lt ? key[r] : o, mx = lt ? o : key[r];
                    key[r] = takeMin ? mn : mx;
                }
            } else if (j >= 4) {
                int lx = j >> 2;
#pragma unroll
                for (int r = 0; r < 4; ++r) {
                    int idx = idxBase + r;
                    uint64_t o = __shfl_xor(key[r], lx, 64);
                    bool takeMin = (((idx & k) == 0) == ((lane & lx) == 0));
                    bool lt = key[r] < o;
                    uint64_t mn = lt ? key[r] : o, mx = lt ? o : key[r];
                    key[r] = takeMin ? mn : mx;
                }
            } else {
#pragma unroll
                for (int r = 0; r < 4; ++r) {
                    if ((r & j) == 0) {
                        int rh = r | j;
                        int idx = idxBase + r;
                        bool up = ((idx & k) == 0);
                        uint64_t a = key[r], c2 = key[rh];
                        bool lt = a < c2;
                        uint64_t mn = lt ? a : c2, mx = lt ? c2 : a;
                        key[r] = up ? mn : mx; key[rh] = up ? mx : mn;
                    }
                }
            }
        }
    }
}

// ===================== K1: decode -> workspace =====================
__global__ __launch_bounds__(BT) void K1decode_PRISM_71511205479155(
    const float* __restrict__ clss, const float* __restrict__ regs,
    const float* __restrict__ qlts, const float* __restrict__ props,
    float4* __restrict__ wbox, uint64_t* __restrict__ wkey, int* __restrict__ wmeta)
{
    __shared__ int s_maxc;
    const int b = blockIdx.x, tid = threadIdx.x, lane = tid & 63, wv = tid >> 6;
    const int idxBase = (wv << 8) | (lane << 2);
    if (tid == 0) s_maxc = 0;
    __syncthreads();

    float thmax = 0.0f;
#pragma unroll
    for (int r = 0; r < 4; ++r) {
        int i = idxBase + r;
        float4 bx; uint64_t k; float mx;
        decode_one(clss, regs, qlts, props, b, i, bx, k, mx);
        wbox[(size_t)b * NPROP + i] = bx;
        wkey[(size_t)b * NPROP + i] = k;
        thmax = fmaxf(thmax, mx);
    }
#pragma unroll
    for (int d = 1; d < 64; d <<= 1) thmax = fmaxf(thmax, __shfl_xor(thmax, d, 64));
    if (lane == 0) atomicMax(&s_maxc, __float_as_int(thmax)); // coords>=0: int cmp == float cmp
    __syncthreads();
    if (tid == 0) wmeta[b * 2] = s_maxc;
}

// ===================== K2: sort -> workspace =====================
__global__ __launch_bounds__(BT) void K2sort_PRISM_71511205479155(
    uint64_t* __restrict__ wkey, int* __restrict__ wmeta)
{
    __shared__ uint64_t skey[NPROP];
    __shared__ int s_nv;
    const int b = blockIdx.x, tid = threadIdx.x, lane = tid & 63, wv = tid >> 6;
    const int idxBase = (wv << 8) | (lane << 2);
    uint64_t* wk = wkey + (size_t)b * NPROP;

    uint64_t key[4];
#pragma unroll
    for (int r = 0; r < 4; ++r) key[r] = wk[idxBase + r];
    if (tid == 0) s_nv = NPROP;

    bitonic2048(key, skey, idxBase, lane);   // contains barriers (covers s_nv init)

#pragma unroll
    for (int r = 0; r < 4; ++r) wk[idxBase + r] = key[r];

    // valid prefix length from registers: first element with top bit set
    {
        int fi = 4;
#pragma unroll
        for (int r = 3; r >= 0; --r) if ((key[r] >> 63) != 0) fi = r;
        uint64_t anyb = __ballot(fi < 4);
        if (anyb) {
            int L = (int)__builtin_ctzll(anyb);
            int fiL = __shfl(fi, L, 64);
            if (lane == 0) atomicMin(&s_nv, (wv << 8) + (L << 2) + fiL);
        }
    }
    __syncthreads();
    if (tid == 0) wmeta[b * 2 + 1] = s_nv;
}

// ===================== K3: NMS + output =====================
__global__ __launch_bounds__(BT) void K3nms_PRISM_71511205479155(
    const float4* __restrict__ wbox, const uint64_t* __restrict__ wkey,
    const int* __restrict__ wmeta, float* __restrict__ out, int B)
{
    __shared__ float4   s_box[NPROP];
    __shared__ uint64_t s_key[NPROP];
    __shared__ uint64_t s_colpart[8 * 64];
    __shared__ uint64_t s_inpart[8];
    __shared__ float4   s_kbox[KDET];
    __shared__ float    s_karea[KDET];
    __shared__ int      s_keep[KDET];
    __shared__ int      s_kept;

    const int b = blockIdx.x, tid = threadIdx.x, lane = tid & 63, wv = tid >> 6;

    for (int t = tid; t < NPROP; t += BT) {
        s_box[t] = wbox[(size_t)b * NPROP + t];
        s_key[t] = wkey[(size_t)b * NPROP + t];
    }
    if (tid == 0) s_kept = 0;
    const int maxc = wmeta[b * 2];
    const int nv   = wmeta[b * 2 + 1];
    __syncthreads();

    const float off = __fadd_rn(__int_as_float(maxc), 1.0f); // class-1 batched-NMS offset

    // ---- windowed greedy NMS (exact reference semantics) ----
    int c = 0;
    while (true) {
        __syncthreads();
        int kept = s_kept;
        if (c >= nv || kept >= KDET) break;
        int W = min(64, nv - c);
        bool have = (lane < W);

        float qx1 = 0.f, qy1 = 0.f, qx2 = 0.f, qy2 = 0.f, qa = 0.f;
        if (have) {
            float4 bx = s_box[(uint32_t)s_key[c + lane]];
            qx1 = __fadd_rn(bx.x, off); qy1 = __fadd_rn(bx.y, off);
            qx2 = __fadd_rn(bx.z, off); qy2 = __fadd_rn(bx.w, off);
            qa  = __fmul_rn(__fsub_rn(qx2, qx1), __fsub_rn(qy2, qy1));
        }

        // in-window rows via shuffle broadcast; accumulate OWN column bits
        uint64_t colpart = 0;
#pragma unroll
        for (int t = 0; t < 8; ++t) {
            int i = wv + (t << 3);
            bool rowok = (i < W);
            int isrc = rowok ? i : 0;
            float rx1 = __shfl(qx1, isrc, 64);
            float ry1 = __shfl(qy1, isrc, 64);
            float rx2 = __shfl(qx2, isrc, 64);
            float ry2 = __shfl(qy2, isrc, 64);
            float ra  = __shfl(qa , isrc, 64);
            float ltx = fmaxf(rx1, qx1), lty = fmaxf(ry1, qy1);
            float rbx = fminf(rx2, qx2), rby = fminf(ry2, qy2);
            float iw = fmaxf(__fsub_rn(rbx, ltx), 0.0f);
            float ih = fmaxf(__fsub_rn(rby, lty), 0.0f);
            float inter = __fmul_rn(iw, ih);
            float denom = __fadd_rn(__fsub_rn(__fadd_rn(ra, qa), inter), 1e-9f);
            float iou   = __fdiv_rn(inter, denom);
            bool pred = rowok && have && (lane > i) && (iou > NMS_TH);
            uint64_t bm = (uint64_t)__ballot(pred);
            colpart |= ((bm >> lane) & 1ull) << isrc;
        }
        s_colpart[(wv << 6) | lane] = colpart;

        // incoming suppression by prior-window keepers
        bool supin = false;
        if (have) {
            for (int ki = wv; ki < kept; ki += 8) {
                float4 ko = s_kbox[ki];
                float  ka = s_karea[ki];
                float ltx = fmaxf(ko.x, qx1), lty = fmaxf(ko.y, qy1);
                float rbx = fminf(ko.z, qx2), rby = fminf(ko.w, qy2);
                float iw = fmaxf(__fsub_rn(rbx, ltx), 0.0f);
                float ih = fmaxf(__fsub_rn(rby, lty), 0.0f);
                float inter = __fmul_rn(iw, ih);
                float denom = __fadd_rn(__fsub_rn(__fadd_rn(ka, qa), inter), 1e-9f);
                supin = supin || (__fdiv_rn(inter, denom) > NMS_TH);
            }
        }
        uint64_t inb = (uint64_t)__ballot(supin);
        if (lane == 0) s_inpart[wv] = inb;
        __syncthreads();

        // ballot-driven greedy resolve — wave 0
        if (wv == 0) {
            uint64_t col = 0, insup = 0;
#pragma unroll
            for (int w2 = 0; w2 < 8; ++w2) {
                col   |= s_colpart[(w2 << 6) | lane];
                insup |= s_inpart[w2];
            }
            bool killed = ((insup >> lane) & 1ull) != 0ull;
            uint64_t remain = (W == 64) ? ~0ull : ((1ull << W) - 1ull);
            int k2 = kept;
            int myNew = 0;
            while (k2 < KDET) {
                uint64_t aliveB = (uint64_t)__ballot(!killed) & remain;
                if (!aliveB) break;
                int i = (int)__builtin_ctzll(aliveB);
                if (lane == (k2 - kept)) myNew = i;
                if (lane == 0) s_keep[k2] = c + i;
                k2++;
                killed = killed || (((col >> i) & 1ull) != 0ull);
                remain = (i < 63) ? (remain & (~0ull << (i + 1))) : 0ull;
            }
            int nNew = k2 - kept;
            if (lane == 0) s_kept = k2;
            if (lane < nNew) {
                float4 bx = s_box[(uint32_t)s_key[c + myNew]];
                float kx1 = __fadd_rn(bx.x, off), ky1 = __fadd_rn(bx.y, off);
                float kx2 = __fadd_rn(bx.z, off), ky2 = __fadd_rn(bx.w, off);
                s_kbox[kept + lane]  = make_float4(kx1, ky1, kx2, ky2);
                s_karea[kept + lane] = __fmul_rn(__fsub_rn(kx2, kx1), __fsub_rn(ky2, ky1));
            }
        }
        c += 64;
    }
    __syncthreads();

    // ---- output write + zero-fill ----
    float* out_boxes  = out;
    float* out_scores = out + (size_t)B * KDET * 4;
    float* out_cls    = out + (size_t)B * KDET * 5;
    int kept = s_kept;
    for (int s = tid; s < KDET; s += BT) {
        float* ob = out_boxes + ((size_t)b * KDET + s) * 4;
        if (s < kept) {
            uint64_t kk = s_key[s_keep[s]];
            float4 bx = s_box[(uint32_t)kk];
            ob[0] = bx.x; ob[1] = bx.y; ob[2] = bx.z; ob[3] = bx.w;
            out_scores[(size_t)b * KDET + s] = dec_score(kk);
            out_cls[(size_t)b * KDET + s]    = 1.0f;
        } else {
            ob[0] = 0.0f; ob[1] = 0.0f; ob[2] = 0.0f; ob[3] = 0.0f;
            out_scores[(size_t)b * KDET + s] = 0.0f;
            out_cls[(size_t)b * KDET + s]    = 0.0f;
        }
    }
}

// ===================== fallback: validated R5 single kernel =====================
__global__ __launch_bounds__(BT) void FB_PRISM_71511205479155_kernel(
    const float* __restrict__ clss, const float* __restrict__ regs,
    const float* __restrict__ qlts, const float* __restrict__ props,
    float* __restrict__ out, int B)
{
    __shared__ float4   sbox[NPROP];
    __shared__ uint64_t skey[NPROP];
    __shared__ uint64_t s_colpart[8 * 64];
    __shared__ uint64_t s_inpart[8];
    __shared__ float4   s_kbox[KDET];
    __shared__ float    s_karea[KDET];
    __shared__ int      s_keep[KDET];
    __shared__ int      s_maxc, s_kept, s_nvalid;

    const int b = blockIdx.x, tid = threadIdx.x, lane = tid & 63, wv = tid >> 6;
    const int idxBase = (wv << 8) | (lane << 2);

    if (tid == 0) { s_maxc = 0; s_kept = 0; s_nvalid = NPROP; }
    __syncthreads();

    uint64_t key[4];
    float thmax = 0.0f;
#pragma unroll
    for (int r = 0; r < 4; ++r) {
        int i = idxBase + r;
        float4 bx; uint64_t k; float mx;
        decode_one(clss, regs, qlts, props, b, i, bx, k, mx);
        sbox[i] = bx; key[r] = k;
        thmax = fmaxf(thmax, mx);
    }
#pragma unroll
    for (int d = 1; d < 64; d <<= 1) thmax = fmaxf(thmax, __shfl_xor(thmax, d, 64));
    if (lane == 0) atomicMax(&s_maxc, __float_as_int(thmax));

    bitonic2048(key, skey, idxBase, lane);

    __syncthreads();
#pragma unroll
    for (int r = 0; r < 4; ++r) skey[idxBase + r] = key[r];
    {
        int fi = 4;
#pragma unroll
        for (int r = 3; r >= 0; --r) if ((key[r] >> 63) != 0) fi = r;
        uint64_t anyb = __ballot(fi < 4);
        if (anyb) {
            int L = (int)__builtin_ctzll(anyb);
            int fiL = __shfl(fi, L, 64);
            if (lane == 0) atomicMin(&s_nvalid, (wv << 8) + (L << 2) + fiL);
        }
    }
    __syncthreads();

    const float off = __fadd_rn(__int_as_float(s_maxc), 1.0f);
    const int nv = s_nvalid;

    int c = 0;
    while (true) {
        __syncthreads();
        int kept = s_kept;
        if (c >= nv || kept >= KDET) break;
        int W = min(64, nv - c);
        bool have = (lane < W);

        float qx1 = 0.f, qy1 = 0.f, qx2 = 0.f, qy2 = 0.f, qa = 0.f;
        if (have) {
            float4 bx = sbox[(uint32_t)skey[c + lane]];
            qx1 = __fadd_rn(bx.x, off); qy1 = __fadd_rn(bx.y, off);
            qx2 = __fadd_rn(bx.z, off); qy2 = __fadd_rn(bx.w, off);
            qa  = __fmul_rn(__fsub_rn(qx2, qx1), __fsub_rn(qy2, qy1));
        }
        uint64_t colpart = 0;
#pragma unroll
        for (int t = 0; t < 8; ++t) {
            int i = wv + (t << 3);
            bool rowok = (i < W);
            int isrc = rowok ? i : 0;
            float rx1 = __shfl(qx1, isrc, 64);
            float ry1 = __shfl(qy1, isrc, 64);
            float rx2 = __shfl(qx2, isrc, 64);
            float ry2 = __shfl(qy2, isrc, 64);
            float ra  = __shfl(qa , isrc, 64);
            float ltx = fmaxf(rx1, qx1), lty = fmaxf(ry1, qy1);
            float rbx = fminf(rx2, qx2), rby = fminf(ry2, qy2);
            float iw = fmaxf(__fsub_rn(rbx, ltx), 0.0f);
            float ih = fmaxf(__fsub_rn(rby, lty), 0.0f);
            float inter = __fmul_rn(iw, ih);
            float denom = __fadd_rn(__fsub_rn(__fadd_rn(ra, qa), inter), 1e-9f);
            float iou   = __fdiv_rn(inter, denom);
            bool pred = rowok && have && (lane > i) && (iou > NMS_TH);
            uint64_t bm = (uint64_t)__ballot(pred);
            colpart |= ((bm >> lane) & 1ull) << isrc;
        }
        s_colpart[(wv << 6) | lane] = colpart;

        bool supin = false;
        if (have) {
            for (int ki = wv; ki < kept; ki += 8) {
                float4 ko = s_kbox[ki];
                float  ka = s_karea[ki];
                float ltx = fmaxf(ko.x, qx1), lty = fmaxf(ko.y, qy1);
                float rbx = fminf(ko.z, qx2), rby = fminf(ko.w, qy2);
                float iw = fmaxf(__fsub_rn(rbx, ltx), 0.0f);
                float ih = fmaxf(__fsub_rn(rby, lty), 0.0f);
                float inter = __fmul_rn(iw, ih);
                float denom = __fadd_rn(__fsub_rn(__fadd_rn(ka, qa), inter), 1e-9f);
                supin = supin || (__fdiv_rn(inter, denom) > NMS_TH);
            }
        }
        uint64_t inb = (uint64_t)__ballot(supin);
        if (lane == 0) s_inpart[wv] = inb;
        __syncthreads();

        if (wv == 0) {
            uint64_t col = 0, insup = 0;
#pragma unroll
            for (int w2 = 0; w2 < 8; ++w2) {
                col   |= s_colpart[(w2 << 6) | lane];
                insup |= s_inpart[w2];
            }
            bool killed = ((insup >> lane) & 1ull) != 0ull;
            uint64_t remain = (W == 64) ? ~0ull : ((1ull << W) - 1ull);
            int k2 = kept;
            int myNew = 0;
            while (k2 < KDET) {
                uint64_t aliveB = (uint64_t)__ballot(!killed) & remain;
                if (!aliveB) break;
                int i = (int)__builtin_ctzll(aliveB);
                if (lane == (k2 - kept)) myNew = i;
                if (lane == 0) s_keep[k2] = c + i;
                k2++;
                killed = killed || (((col >> i) & 1ull) != 0ull);
                remain = (i < 63) ? (remain & (~0ull << (i + 1))) : 0ull;
            }
            int nNew = k2 - kept;
            if (lane == 0) s_kept = k2;
            if (lane < nNew) {
                float4 bx = sbox[(uint32_t)skey[c + myNew]];
                float kx1 = __fadd_rn(bx.x, off), ky1 = __fadd_rn(bx.y, off);
                float kx2 = __fadd_rn(bx.z, off), ky2 = __fadd_rn(bx.w, off);
                s_kbox[kept + lane]  = make_float4(kx1, ky1, kx2, ky2);
                s_karea[kept + lane] = __fmul_rn(__fsub_rn(kx2, kx1), __fsub_rn(ky2, ky1));
            }
        }
        c += 64;
    }
    __syncthreads();

    float* out_boxes  = out;
    float* out_scores = out + (size_t)B * KDET * 4;
    float* out_cls    = out + (size_t)B * KDET * 5;
    int kept = s_kept;
    for (int s = tid; s < KDET; s += BT) {
        float* ob = out_boxes + ((size_t)b * KDET + s) * 4;
        if (s < kept) {
            uint64_t kk = skey[s_keep[s]];
            float4 bx = sbox[(uint32_t)kk];
            ob[0] = bx.x; ob[1] = bx.y; ob[2] = bx.z; ob[3] = bx.w;
            out_scores[(size_t)b * KDET + s] = dec_score(kk);
            out_cls[(size_t)b * KDET + s]    = 1.0f;
        } else {
            ob[0] = 0.0f; ob[1] = 0.0f; ob[2] = 0.0f; ob[3] = 0.0f;
            out_scores[(size_t)b * KDET + s] = 0.0f;
            out_cls[(size_t)b * KDET + s]    = 0.0f;
        }
    }
}

extern "C" void kernel_launch(void* const* d_in, const int* in_sizes, int n_in,
                              void* d_out, int out_size, void* d_ws, size_t ws_size,
                              hipStream_t stream) {
    const float* clss  = (const float*)d_in[0];  // [B,N,2]
    const float* regs  = (const float*)d_in[1];  // [B,N,4]
    const float* qlts  = (const float*)d_in[2];  // [B,N,1]
    const float* props = (const float*)d_in[3];  // [B,N,4]
    float* out = (float*)d_out;

    int B = in_sizes[0] / (NPROP * NCLS);
    size_t need = (size_t)B * NPROP * 24 + (size_t)B * 2 * sizeof(int);

    if (ws_size >= need) {
        float4*   wbox  = (float4*)d_ws;
        uint64_t* wkey  = (uint64_t*)((char*)d_ws + (size_t)B * NPROP * 16);
        int*      wmeta = (int*)((char*)d_ws + (size_t)B * NPROP * 24);
        K1decode_PRISM_71511205479155<<<B, BT, 0, stream>>>(clss, regs, qlts, props, wbox, wkey, wmeta);
        K2sort_PRISM_71511205479155<<<B, BT, 0, stream>>>(wkey, wmeta);
        K3nms_PRISM_71511205479155<<<B, BT, 0, stream>>>(wbox, wkey, wmeta, out, B);
    } else {
        FB_PRISM_71511205479155_kernel<<<B, BT, 0, stream>>>(clss, regs, qlts, props, out, B);
    }
}